// Round 1
// baseline (2364.596 us; speedup 1.0000x reference)
//
#include <hip/hip_runtime.h>
#include <cstdint>

// FPS: B=8, N=131072, NPOINT=1024.
// State (xyz + mindist) register-resident: 8 batches x 16 blocks x 1024 thr x 8 pts.
// Per round: register update + wave/block reduce + one u64 relaxed atomic per block,
// spin on 16 slots (one 128B line per batch), winner coords re-read from read-only xyz.
// Packed slot u64: [tag:15 bits][fp32 dist bits:32][(~idx)&0x1FFFF:17] -> unsigned max
// == (dist desc, idx asc) lexicographic, matching np.argmax first-max semantics.

constexpr int kB = 8;
constexpr int kN = 131072;
constexpr int kNpoint = 1024;
constexpr int kBlocksPerBatch = 16;
constexpr int kThreads = 1024;
constexpr int kPPT = 8;                              // points per thread
constexpr int kPtsPerBlock = kThreads * kPPT;        // 8192

__device__ __forceinline__ uint64_t u64max(uint64_t a, uint64_t b) {
    return a > b ? a : b;
}

__device__ __forceinline__ uint64_t shfl_xor_u64(uint64_t v, int m) {
    int lo = __shfl_xor((int)(uint32_t)v, m, 64);
    int hi = __shfl_xor((int)(uint32_t)(v >> 32), m, 64);
    return ((uint64_t)(uint32_t)hi << 32) | (uint32_t)lo;
}

__global__ __launch_bounds__(kThreads, 4) void fps_kernel(
        const float* __restrict__ xyz, float* __restrict__ out,
        uint64_t* __restrict__ slots) {
    const int b    = blockIdx.x & 7;    // batch -> likely one XCD per batch (round-robin)
    const int blk  = blockIdx.x >> 3;   // block within batch, 0..15
    const int tid  = threadIdx.x;
    const int lane = tid & 63;
    const int wid  = tid >> 6;

    const float* __restrict__ base = xyz + (size_t)b * kN * 3;

    // Register-resident points + running min-dist.
    float x[kPPT], y[kPPT], z[kPPT], md[kPPT];
#pragma unroll
    for (int j = 0; j < kPPT; ++j) {
        const int p = blk * kPtsPerBlock + j * kThreads + tid;
        x[j] = base[3 * p + 0];
        y[j] = base[3 * p + 1];
        z[j] = base[3 * p + 2];
        md[j] = __builtin_inff();
    }

    // First sample is always point 0 (scan emits incoming 'farthest' before update).
    float cx = base[0], cy = base[1], cz = base[2];
    if (blk == 0 && tid == 0) {
        float* o = out + (size_t)b * kNpoint * 3;
        o[0] = cx; o[1] = cy; o[2] = cz;
    }

    __shared__ uint64_t warr[kThreads / 64];  // per-wave bests
    __shared__ float cent[3];

    for (int t = 1; t < kNpoint; ++t) {
        // --- update mindist + thread-local packed argmax (exact fp32, no FMA) ---
        uint64_t best = 0;
#pragma unroll
        for (int j = 0; j < kPPT; ++j) {
            const float dx = __fsub_rn(x[j], cx);
            const float dy = __fsub_rn(y[j], cy);
            const float dz = __fsub_rn(z[j], cz);
            const float d  = __fadd_rn(__fadd_rn(__fmul_rn(dx, dx), __fmul_rn(dy, dy)),
                                       __fmul_rn(dz, dz));
            const float m = fminf(md[j], d);
            md[j] = m;
            const uint32_t p = (uint32_t)(blk * kPtsPerBlock + j * kThreads + tid);
            const uint64_t pk = ((uint64_t)__float_as_uint(m) << 17) | ((~p) & 0x1FFFFu);
            best = u64max(best, pk);
        }

        // --- wave reduce (64 lanes) ---
#pragma unroll
        for (int s = 32; s > 0; s >>= 1) best = u64max(best, shfl_xor_u64(best, s));
        if (lane == 0) warr[wid] = best;
        __syncthreads();  // B1: all wave bests in LDS

        if (wid == 0) {
            // parity double-buffer: a block can be at most one round ahead
            uint64_t* slotbuf = slots + ((size_t)(t & 1) * kB + b) * kBlocksPerBatch;

            uint64_t v = (lane < kThreads / 64) ? warr[lane] : 0;
#pragma unroll
            for (int s = 8; s > 0; s >>= 1) v = u64max(v, shfl_xor_u64(v, s));

            if (lane == 0) {
                // single-u64 payload -> relaxed is sufficient, no fence
                __hip_atomic_store(&slotbuf[blk], ((uint64_t)t << 49) | v,
                                   __ATOMIC_RELAXED, __HIP_MEMORY_SCOPE_AGENT);
            }

            // spin until all 16 blocks of this batch posted round t
            uint64_t got = 0;
            bool need = lane < kBlocksPerBatch;
            while (__any(need)) {
                if (need) {
                    uint64_t sv = __hip_atomic_load(&slotbuf[lane], __ATOMIC_RELAXED,
                                                    __HIP_MEMORY_SCOPE_AGENT);
                    if ((sv >> 49) == (uint64_t)t) { got = sv; need = false; }
                }
            }
#pragma unroll
            for (int s = 8; s > 0; s >>= 1) got = u64max(got, shfl_xor_u64(got, s));

            if (lane == 0) {
                const uint32_t widx = 131071u - (uint32_t)(got & 0x1FFFFu);
                const float wx = base[3 * (size_t)widx + 0];
                const float wy = base[3 * (size_t)widx + 1];
                const float wz = base[3 * (size_t)widx + 2];
                cent[0] = wx; cent[1] = wy; cent[2] = wz;
                if (blk == 0) {
                    float* o = out + ((size_t)b * kNpoint + t) * 3;
                    o[0] = wx; o[1] = wy; o[2] = wz;
                }
            }
        }
        __syncthreads();  // B2: centroid ready for everyone
        cx = cent[0]; cy = cent[1]; cz = cent[2];
    }
}

extern "C" void kernel_launch(void* const* d_in, const int* in_sizes, int n_in,
                              void* d_out, int out_size, void* d_ws, size_t ws_size,
                              hipStream_t stream) {
    const float* xyz = (const float*)d_in[0];
    float* out = (float*)d_out;
    uint64_t* slots = (uint64_t*)d_ws;  // 2 * 8 * 16 u64 = 2 KiB used
    fps_kernel<<<dim3(kB * kBlocksPerBatch), dim3(kThreads), 0, stream>>>(xyz, out, slots);
}

// Round 2
// 2026.632 us; speedup vs baseline: 1.1668x; 1.1668x over previous
//
#include <hip/hip_runtime.h>
#include <cstdint>

// FPS: B=8, N=131072, NPOINT=1024.  Exact-index replication of the jax reference.
// State register-resident: 8 batches x 16 blocks x 1024 thr x 8 pts (x,y,z,mindist).
// Per round (one __syncthreads only):
//   update (no-FMA exact fp32) + per-thread (bm,bj) argmax
//   -> 6-level DPP wave max (row_shr/row_bcast, result in lane 63)
//   -> ds_atomic_max into tag-packed LDS u64 (parity dbuf, monotone tags, no reset)
//   -> barrier -> tid0 posts LDS value to global slot (relaxed agent atomic store)
//   -> ALL waves spin on the 16 slots (lanes 0-15), 4-level DPP group max,
//      readfirstlane broadcast -> winner coords re-read from read-only xyz.
// Packed u64: [t:15][fp32 dist bits:32][(~idx)&0x1FFFF:17]  -> unsigned max ==
// (round, dist desc, idx asc), matching np.argmax first-max tie-break. Poisoned
// workspace (tag 0x5555) never matches a live round tag.

constexpr int kB = 8;
constexpr int kN = 131072;
constexpr int kNpoint = 1024;
constexpr int kBlocksPerBatch = 16;
constexpr int kThreads = 1024;
constexpr int kPPT = 8;
constexpr int kPtsPerBlock = kThreads * kPPT;  // 8192

__device__ __forceinline__ uint64_t u64max(uint64_t a, uint64_t b) {
    return a > b ? a : b;
}

// DPP move of a u64 (both halves, same ctrl); invalid source lanes yield 0,
// which is the identity for our non-negative packed values.
template <int CTRL>
__device__ __forceinline__ uint64_t dpp_u64(uint64_t v) {
    int lo = __builtin_amdgcn_update_dpp(0, (int)(uint32_t)v, CTRL, 0xF, 0xF, false);
    int hi = __builtin_amdgcn_update_dpp(0, (int)(uint32_t)(v >> 32), CTRL, 0xF, 0xF, false);
    return ((uint64_t)(uint32_t)hi << 32) | (uint32_t)lo;
}

// Full-wave max; result valid in lane 63 (classic row_shr/row_bcast ladder).
__device__ __forceinline__ uint64_t wave_max_to_lane63(uint64_t v) {
    v = u64max(v, dpp_u64<0x111>(v));  // row_shr:1
    v = u64max(v, dpp_u64<0x112>(v));  // row_shr:2
    v = u64max(v, dpp_u64<0x114>(v));  // row_shr:4
    v = u64max(v, dpp_u64<0x118>(v));  // row_shr:8
    v = u64max(v, dpp_u64<0x142>(v));  // row_bcast:15
    v = u64max(v, dpp_u64<0x143>(v));  // row_bcast:31
    return v;
}

// Max over each aligned group of 16 lanes (butterfly xor1,2,4,8).
__device__ __forceinline__ uint64_t group16_max(uint64_t v) {
    v = u64max(v, dpp_u64<0xB1>(v));   // quad_perm(1,0,3,2)  = xor 1
    v = u64max(v, dpp_u64<0x4E>(v));   // quad_perm(2,3,0,1)  = xor 2
    v = u64max(v, dpp_u64<0x141>(v));  // row_half_mirror (^7 == xor4 after quads uniform)
    v = u64max(v, dpp_u64<0x140>(v));  // row_mirror      (^15 == xor8 after halves uniform)
    return v;
}

__global__ __launch_bounds__(kThreads, 4) void fps_kernel(
        const float* __restrict__ xyz, float* __restrict__ out,
        uint64_t* __restrict__ slots) {
    const int b    = blockIdx.x & 7;    // batch: all 16 blocks of a batch on one XCD
    const int blk  = blockIdx.x >> 3;   // block within batch, 0..15
    const int tid  = threadIdx.x;
    const int lane = tid & 63;

    const float* __restrict__ base = xyz + (size_t)b * kN * 3;

    float x[kPPT], y[kPPT], z[kPPT], md[kPPT];
#pragma unroll
    for (int j = 0; j < kPPT; ++j) {
        const int p = blk * kPtsPerBlock + j * kThreads + tid;
        x[j] = base[3 * p + 0];
        y[j] = base[3 * p + 1];
        z[j] = base[3 * p + 2];
        md[j] = __builtin_inff();
    }

    __shared__ uint64_t lbest[2];
    if (tid == 0) { lbest[0] = 0; lbest[1] = 0; }

    // First sample is always point 0.
    float cx = base[0], cy = base[1], cz = base[2];
    if (blk == 0 && tid == 0) {
        float* o = out + (size_t)b * kNpoint * 3;
        o[0] = cx; o[1] = cy; o[2] = cz;
    }
    __syncthreads();  // lbest init visible

    for (int t = 1; t < kNpoint; ++t) {
        // --- mindist update + per-thread argmax (exact fp32, no FMA) ---
        float bm = -1.0f;
        int bj = 0;
#pragma unroll
        for (int j = 0; j < kPPT; ++j) {
            const float dx = __fsub_rn(x[j], cx);
            const float dy = __fsub_rn(y[j], cy);
            const float dz = __fsub_rn(z[j], cz);
            const float d  = __fadd_rn(__fadd_rn(__fmul_rn(dx, dx), __fmul_rn(dy, dy)),
                                       __fmul_rn(dz, dz));
            const float m = fminf(md[j], d);
            md[j] = m;
            const bool g = m > bm;        // strict > keeps smallest j among ties
            bj = g ? j : bj;
            bm = g ? m : bm;
        }
        const uint32_t p = (uint32_t)(blk * kPtsPerBlock + bj * kThreads + tid);
        uint64_t pk = ((uint64_t)t << 49) |
                      ((uint64_t)__float_as_uint(bm) << 17) |
                      ((~p) & 0x1FFFFu);

        // --- wave max -> lane 63 -> LDS atomic max (tag-packed, parity dbuf) ---
        pk = wave_max_to_lane63(pk);
        if (lane == 63) {
            __hip_atomic_fetch_max(&lbest[t & 1], pk, __ATOMIC_RELAXED,
                                   __HIP_MEMORY_SCOPE_WORKGROUP);
        }
        __syncthreads();  // the one barrier: block best complete in LDS

        uint64_t* slotbuf = slots + ((size_t)(t & 1) * kB + b) * kBlocksPerBatch;
        if (tid == 0) {
            // already tagged with t; single-u64 payload -> relaxed suffices
            __hip_atomic_store(&slotbuf[blk], lbest[t & 1], __ATOMIC_RELAXED,
                               __HIP_MEMORY_SCOPE_AGENT);
        }

        // --- every wave spins on the 16 slots (lanes 0-15) ---
        uint64_t got = 0;
        bool need = lane < kBlocksPerBatch;
        while (__any(need)) {
            if (need) {
                uint64_t sv = __hip_atomic_load(&slotbuf[lane], __ATOMIC_RELAXED,
                                                __HIP_MEMORY_SCOPE_AGENT);
                if ((sv >> 49) == (uint64_t)t) { got = sv; need = false; }
            }
        }
        got = group16_max(got);  // lanes 0-15 now hold the batch winner

        // broadcast via scalar regs; winner coords from read-only xyz
        const uint32_t lo = (uint32_t)got;
        const uint32_t widx = 131071u - (__builtin_amdgcn_readfirstlane((int)lo) & 0x1FFFFu);
        cx = base[3 * (size_t)widx + 0];
        cy = base[3 * (size_t)widx + 1];
        cz = base[3 * (size_t)widx + 2];
        if (blk == 0 && tid == 0) {
            float* o = out + ((size_t)b * kNpoint + t) * 3;
            o[0] = cx; o[1] = cy; o[2] = cz;
        }
    }
}

extern "C" void kernel_launch(void* const* d_in, const int* in_sizes, int n_in,
                              void* d_out, int out_size, void* d_ws, size_t ws_size,
                              hipStream_t stream) {
    const float* xyz = (const float*)d_in[0];
    float* out = (float*)d_out;
    uint64_t* slots = (uint64_t*)d_ws;  // 2 * 8 * 16 u64 = 2 KiB used
    fps_kernel<<<dim3(kB * kBlocksPerBatch), dim3(kThreads), 0, stream>>>(xyz, out, slots);
}